// Round 24
// baseline (136.707 us; speedup 1.0000x reference)
//
#include <hip/hip_runtime.h>
#include <hip/hip_bf16.h>

#define SEQ 4096
#define NB 2
#define DM 512
#define NH 8
#define DK 64

typedef __bf16 bf16;
typedef __bf16 bf16x4 __attribute__((ext_vector_type(4)));
typedef __bf16 bf16x8 __attribute__((ext_vector_type(8)));
typedef float  f32x4 __attribute__((ext_vector_type(4)));

__device__ __forceinline__ f32x4 mfma16(bf16x8 a, bf16x8 b, f32x4 c) {
    return __builtin_amdgcn_mfma_f32_16x16x32_bf16(a, b, c, 0, 0, 0);
}

__device__ __forceinline__ float fexp2(float x) {
    return __builtin_amdgcn_exp2f(x);   // raw v_exp_f32 (2^x)
}

// Async global->LDS, 16B per lane. LDS dest is wave-uniform base + lane*16.
__device__ __forceinline__ void gload_lds16(const bf16* g, bf16* l) {
    __builtin_amdgcn_global_load_lds(
        (const __attribute__((address_space(1))) void*)g,
        (__attribute__((address_space(3))) void*)l, 16, 0, 0);
}

// LDS rows are 64 bf16 (128 B). XOR-swizzle 16B slot by row (G4 fix).
__device__ __forceinline__ int swzE(int row, int e) {
    return row * 64 + (e ^ ((row & 7) << 3));
}

// Load 8 contiguous fp32 -> bf16x8 (hi only).
__device__ __forceinline__ bf16x8 cvt8(const float* __restrict__ p) {
    const float4 v0 = *(const float4*)p;
    const float4 v1 = *(const float4*)(p + 4);
    return (bf16x8){(bf16)v0.x, (bf16)v0.y, (bf16)v0.z, (bf16)v0.w,
                    (bf16)v1.x, (bf16)v1.y, (bf16)v1.z, (bf16)v1.w};
}

// ---------------------------------------------------------------------------
// Prep, one launch: weight transposes to bf16 AND x -> bf16 copy.
// by 0..23: Wqkv -> Wqh[1536][512]; by 24..31: Wout -> Woh[512][512];
// by 32..39: x (8192x512 fp32) -> xh bf16.
// ---------------------------------------------------------------------------
__global__ __launch_bounds__(256)
void prep_all(const float* __restrict__ Wqkv, const float* __restrict__ Wout,
              const float* __restrict__ x,
              bf16* __restrict__ Wqh, bf16* __restrict__ Woh,
              bf16* __restrict__ xh) {
    __shared__ float T[64][65];
    const int t = threadIdx.x;
    const int bx = blockIdx.x, by = blockIdx.y;

    if (by >= 32) {   // x conversion
        const int r0 = ((by - 32) * 8 + bx) * 128;
        #pragma unroll
        for (int i = 0; i < 32; ++i) {
            const int idx = i * 256 + t;
            const int rr = idx >> 6;
            const int cc = (idx & 63) * 8;
            const size_t o = (size_t)(r0 + rr) * DM + cc;
            *(bf16x8*)&xh[o] = cvt8(&x[o]);
        }
        return;
    }

    const float* W; bf16* D; int N, n0;
    if (by < 24) { W = Wqkv; D = Wqh; N = 3 * DM; n0 = by * 64; }
    else         { W = Wout; D = Woh; N = DM;     n0 = (by - 24) * 64; }
    const int k0 = bx * 64;
    #pragma unroll
    for (int i = 0; i < 4; ++i) {
        int r = i * 16 + (t >> 4);
        int c = (t & 15) * 4;
        float4 v = *(const float4*)&W[(size_t)(k0 + r) * N + n0 + c];
        T[r][c + 0] = v.x; T[r][c + 1] = v.y; T[r][c + 2] = v.z; T[r][c + 3] = v.w;
    }
    __syncthreads();
    #pragma unroll
    for (int i = 0; i < 4; ++i) {
        int n = i * 16 + (t >> 4);
        int c = (t & 15) * 4;
        bf16x4 hv = (bf16x4){(bf16)T[c + 0][n], (bf16)T[c + 1][n],
                             (bf16)T[c + 2][n], (bf16)T[c + 3][n]};
        *(bf16x4*)&D[(size_t)(n0 + n) * DM + k0 + c] = hv;
    }
}

// ---------------------------------------------------------------------------
// QKV GEMM: all-bf16 operands, pure global_load_lds staging; fused bf16
// Q/K/V emission via LDS bounce (Q scaled by log2e/8; V transposed + R20
// slot permutation).
// ---------------------------------------------------------------------------
__global__ __launch_bounds__(256, 2)
void gemm_qkv(const bf16* __restrict__ A, const bf16* __restrict__ Bth,
              bf16* __restrict__ Qout, bf16* __restrict__ Kout,
              bf16* __restrict__ Vout, int M, int N, int K) {
    __shared__ __align__(16) char smem_raw[36864];   // 36 KB
    bf16* Ah = (bf16*)smem_raw;
    bf16* Bh = Ah + 128 * 64;

    const int t = threadIdx.x;
    const int lane = t & 63, w = t >> 6;
    const int l15 = lane & 15, g = lane >> 4;
    const int wm = (w >> 1) * 64, wn = (w & 1) * 64;
    const int rowA = blockIdx.y * 128;
    const int colB = blockIdx.x * 128;

    const int sr2 = t >> 3;
    const int sc8 = (t & 7) * 8;
    const int scs = sc8 ^ ((sr2 & 7) << 3);
    const int dstE = t * 8;

    f32x4 acc[4][4] = {};

    for (int k0 = 0; k0 < K; k0 += 64) {
        __syncthreads();
        #pragma unroll
        for (int c = 0; c < 4; ++c) {
            gload_lds16(&A[(size_t)(rowA + c * 32 + sr2) * K + k0 + scs],
                        Ah + c * 2048 + dstE);
            gload_lds16(&Bth[(size_t)(colB + c * 32 + sr2) * K + k0 + scs],
                        Bh + c * 2048 + dstE);
        }
        __syncthreads();
        #pragma unroll
        for (int kst = 0; kst < 2; ++kst) {
            bf16x8 ah[4];
            #pragma unroll
            for (int mi = 0; mi < 4; ++mi) {
                int off = swzE(wm + mi * 16 + l15, kst * 32 + g * 8);
                ah[mi] = *(const bf16x8*)&Ah[off];
            }
            #pragma unroll
            for (int ni = 0; ni < 4; ++ni) {
                int off = swzE(wn + ni * 16 + l15, kst * 32 + g * 8);
                bf16x8 bh = *(const bf16x8*)&Bh[off];
                #pragma unroll
                for (int mi = 0; mi < 4; ++mi)
                    acc[mi][ni] = mfma16(ah[mi], bh, acc[mi][ni]);
            }
        }
    }

    // ---- fused Q/K/V bf16 epilogue via LDS bounce ----
    const int sec = colB >> 9;           // 0=Q, 1=K, 2=V
    const float scl = (sec == 0) ? 0.125f * 1.44269504088896f : 1.0f;
    bf16* TB = (bf16*)smem_raw;          // [128][136] bf16
    __syncthreads();
    #pragma unroll
    for (int mi = 0; mi < 4; ++mi)
        #pragma unroll
        for (int ni = 0; ni < 4; ++ni)
            #pragma unroll
            for (int r = 0; r < 4; ++r) {
                const int rr = wm + mi * 16 + g * 4 + r;
                const int cr = wn + ni * 16 + l15;
                const float v = acc[mi][ni][r] * scl;
                if (sec < 2) {
                    TB[rr * 136 + cr] = (bf16)v;
                } else {
                    const int kk = rr & 63;
                    const int nn = kk >> 4;
                    const int sl = ((nn & 1) << 5) | (((kk >> 2) & 3) << 3)
                                 | ((nn >> 1) << 2) | (kk & 3);
                    TB[cr * 136 + (rr >> 6) * 64 + sl] = (bf16)v;
                }
            }
    __syncthreads();
    const int b_ = rowA >> 12;
    const int sbase = rowA & 4095;
    #pragma unroll
    for (int pass = 0; pass < 8; ++pass) {
        const int rowi = pass * 16 + (t >> 4);
        const int e8 = (t & 15) * 8;
        bf16x8 v = *(const bf16x8*)&TB[rowi * 136 + e8];
        if (sec < 2) {
            const int ckv = (colB & 511) + e8;
            const int h_ = ckv >> 6, d8 = ckv & 63;
            bf16* dst = (sec == 0) ? Qout : Kout;
            *(bf16x8*)&dst[(((size_t)b_ * NH + h_) * SEQ + sbase + rowi) * DK + d8] = v;
        } else {
            const int cv = (colB - 1024) + rowi;
            const int h_ = cv >> 6, d_ = cv & 63;
            *(bf16x8*)&Vout[(((size_t)b_ * NH + h_) * DK + d_) * SEQ + sbase + e8] = v;
        }
    }
}

// ---------------------------------------------------------------------------
// Out GEMM: both operands bf16 -> pure gload_lds staging. fp32 C.
// ---------------------------------------------------------------------------
__global__ __launch_bounds__(256, 2)
void gemm_out(const bf16* __restrict__ A, const bf16* __restrict__ Bth,
              float* __restrict__ C, int M, int N, int K) {
    __shared__ __align__(16) bf16 Ah[128 * 64], Bh[128 * 64];

    const int t = threadIdx.x;
    const int lane = t & 63, w = t >> 6;
    const int l15 = lane & 15, g = lane >> 4;
    const int wm = (w >> 1) * 64, wn = (w & 1) * 64;
    const int rowA = blockIdx.y * 128;
    const int colB = blockIdx.x * 128;

    const int sr2 = t >> 3;
    const int sc8 = (t & 7) * 8;
    const int scs = sc8 ^ ((sr2 & 7) << 3);
    const int dstE = t * 8;

    f32x4 acc[4][4] = {};

    for (int k0 = 0; k0 < K; k0 += 64) {
        __syncthreads();
        #pragma unroll
        for (int c = 0; c < 4; ++c) {
            gload_lds16(&A[(size_t)(rowA + c * 32 + sr2) * K + k0 + scs],
                        Ah + c * 2048 + dstE);
            gload_lds16(&Bth[(size_t)(colB + c * 32 + sr2) * K + k0 + scs],
                        Bh + c * 2048 + dstE);
        }
        __syncthreads();
        #pragma unroll
        for (int kst = 0; kst < 2; ++kst) {
            bf16x8 ah[4];
            #pragma unroll
            for (int mi = 0; mi < 4; ++mi) {
                int off = swzE(wm + mi * 16 + l15, kst * 32 + g * 8);
                ah[mi] = *(const bf16x8*)&Ah[off];
            }
            #pragma unroll
            for (int ni = 0; ni < 4; ++ni) {
                int off = swzE(wn + ni * 16 + l15, kst * 32 + g * 8);
                bf16x8 bh = *(const bf16x8*)&Bh[off];
                #pragma unroll
                for (int mi = 0; mi < 4; ++mi)
                    acc[mi][ni] = mfma16(ah[mi], bh, acc[mi][ni]);
            }
        }
    }
    #pragma unroll
    for (int mi = 0; mi < 4; ++mi)
        #pragma unroll
        for (int ni = 0; ni < 4; ++ni)
            #pragma unroll
            for (int r = 0; r < 4; ++r) {
                int row = rowA + wm + mi * 16 + g * 4 + r;
                int col = colB + wn + ni * 16 + l15;
                C[(size_t)row * N + col] = acc[mi][ni][r];
            }
}

// ---------------------------------------------------------------------------
// MFMA flash attention, R24: per-wave code IDENTICAL to R22/R23; block
// geometry changed 512->256 threads (4 waves x 16 q-rows = 64 q-rows/block),
// grid 1024 -> 4 INDEPENDENT blocks/CU (LDS 4x32=128 KB). Rationale: pipes
// measured additive (Mfma 45% + VALU 44%); barrier-locked waves convoy
// through MFMA/VALU phases; 4 un-synced blocks drift out of phase -> m114
// cross-wave pipe overlap. Staging: 256 threads cover a 64x64 tile in 2
// passes (row slab stride 32 keeps the row&7 pre-swizzle invariant).
// ---------------------------------------------------------------------------
__global__ __launch_bounds__(256)
void flash_mfma(const bf16* __restrict__ Qh,
                const bf16* __restrict__ Kh, const bf16* __restrict__ Vth,
                bf16* __restrict__ att) {
    extern __shared__ bf16 smem[];
    bf16* KhS = smem;              // [2][64*64] dbuf, 16 KB
    bf16* VhS = smem + 8192;       // [2][64*64] dbuf, 16 KB  -> total 32 KB

    // XCD-bijective swizzle: nwg = 1024 (divisible by 8).
    const int nwg = (int)gridDim.x;
    const int cpx = nwg >> 3;
    const int bid = (int)blockIdx.x;
    const int wg = (bid & 7) * cpx + (bid >> 3);
    const int qt = wg & 63;        // 64 q-tiles of 64 rows
    const int bh = wg >> 6;

    const int t = threadIdx.x, lane = t & 63, w = t >> 6;   // 4 waves
    const int l15 = lane & 15, g = lane >> 4;
    const int q0 = qt * 64;
    const int wq = w * 16;   // each wave owns 16 q-rows

    // Q fragments: pre-scaled bf16, direct load (B-operand for swapped QK^T)
    bf16x8 qh[2];
    {
        const size_t qbase = ((size_t)bh * SEQ + q0 + wq + l15) * DK + g * 8;
        qh[0] = *(const bf16x8*)&Qh[qbase];
        qh[1] = *(const bf16x8*)&Qh[qbase + 32];
    }

    const bf16 one = (bf16)1.0f;
    const bf16x8 ones = (bf16x8){one, one, one, one, one, one, one, one};

    f32x4 o[4] = {};
    f32x4 lacc = {0.f, 0.f, 0.f, 0.f};

    // Staging (256 threads, 2 passes per 64x64 tile): LDS dest = wave base +
    // lane*16B; global source column pre-swizzled (G21 both-sides rule).
    const int sr = t >> 3;               // 0..31
    const int sc8 = (t & 7) * 8;
    const int scs = sc8 ^ ((sr & 7) << 3);
    const size_t kgo = ((size_t)bh * SEQ + sr) * DK + scs;
    const size_t vgo = ((size_t)bh * DK + sr) * SEQ + scs;
    const int dstE = t * 8;              // byte t*16 within a 4 KB half

    auto stage = [&](int kt, int c) {
        const int cb = c * 4096;
        #pragma unroll
        for (int p = 0; p < 2; ++p) {
            gload_lds16(Kh + kgo + ((size_t)kt * 64 + p * 32) * DK,
                        KhS + cb + p * 2048 + dstE);
            gload_lds16(Vth + vgo + (size_t)p * 32 * SEQ + kt * 64,
                        VhS + cb + p * 2048 + dstE);
        }
    };

    const int NT = SEQ / 64;
    stage(0, 0);
    __syncthreads();   // drain tile-0 DMA

    for (int kt = 0; kt < NT; ++kt) {
        const int c = kt & 1;
        if (kt + 1 < NT) stage(kt + 1, c ^ 1);   // async loads overlap compute
        const int cb = c * 4096;

        // ---- scores, SWAPPED: s[ni] = K_tile(ni) @ Q -> [k-row][q-col] ----
        f32x4 s[4] = {};
        __builtin_amdgcn_s_setprio(1);
        #pragma unroll
        for (int kst = 0; kst < 2; ++kst) {
            #pragma unroll
            for (int ni = 0; ni < 4; ++ni) {
                int off = cb + swzE(ni * 16 + l15, kst * 32 + g * 8);
                bf16x8 kh_ = *(const bf16x8*)&KhS[off];
                s[ni] = mfma16(kh_, qh[kst], s[ni]);
            }
        }
        __builtin_amdgcn_s_setprio(0);

        // ---- P = exp2(s), packed IN REGISTERS to the PV A-fragment ----
        bf16x8 pa[2];
        #pragma unroll
        for (int ni = 0; ni < 4; ++ni)
            #pragma unroll
            for (int r = 0; r < 4; ++r)
                pa[ni & 1][(ni >> 1) * 4 + r] = (bf16)fexp2(s[ni][r]);

        // ---- O += P @ V; l += P @ 1 (row sums on the matrix pipe) ----
        __builtin_amdgcn_s_setprio(1);
        #pragma unroll
        for (int kst = 0; kst < 2; ++kst) {
            #pragma unroll
            for (int ni = 0; ni < 4; ++ni) {
                int off = cb + swzE(ni * 16 + l15, kst * 32 + g * 8);
                bf16x8 vh_ = *(const bf16x8*)&VhS[off];
                o[ni] = mfma16(pa[kst], vh_, o[ni]);
            }
            lacc = mfma16(pa[kst], ones, lacc);
        }
        __builtin_amdgcn_s_setprio(0);

        __syncthreads();   // drains next-tile DMA; fences buffer reuse
    }

    // ---- epilogue: normalize, store bf16 ----
    const int b = bh >> 3, h = bh & 7;
    #pragma unroll
    for (int r = 0; r < 4; ++r) {
        const float inv = 1.0f / lacc[r];
        const int row = q0 + wq + g * 4 + r;
        #pragma unroll
        for (int ni = 0; ni < 4; ++ni)
            att[(size_t)(b * SEQ + row) * DM + h * DK + ni * 16 + l15] =
                (bf16)(o[ni][r] * inv);
    }
}

// ---------------------------------------------------------------------------
extern "C" void kernel_launch(void* const* d_in, const int* in_sizes, int n_in,
                              void* d_out, int out_size, void* d_ws, size_t ws_size,
                              hipStream_t stream) {
    const float* x    = (const float*)d_in[0];
    const float* Wqkv = (const float*)d_in[1];
    const float* Wout = (const float*)d_in[2];
    float* out = (float*)d_out;

    char* ws = (char*)d_ws;
    bf16* Qhp  = (bf16*)(ws);                            // 8 MB
    bf16* xh   = (bf16*)(ws + (size_t)16 * 1048576);     // 8 MB
    bf16* attn = (bf16*)(ws + (size_t)48 * 1048576);     // 8 MB
    bf16* Khp  = (bf16*)(ws + (size_t)64 * 1048576);     // 8 MB
    bf16* Vthp = (bf16*)(ws + (size_t)80 * 1048576);     // 8 MB
    bf16* Wqh  = (bf16*)(ws + (size_t)96 * 1048576);     // 1.5 MB
    bf16* Woh  = (bf16*)(ws + (size_t)100 * 1048576);    // 0.5 MB

    const int M = NB * SEQ;   // 8192
    const int FLASH_LDS = 32768;   // 32 KB: Kh[2] + Vh[2]

    hipFuncSetAttribute((const void*)flash_mfma,
                        hipFuncAttributeMaxDynamicSharedMemorySize, FLASH_LDS);

    // weight transposes + x bf16 conversion, one launch
    prep_all<<<dim3(8, 40), 256, 0, stream>>>(Wqkv, Wout, x, Wqh, Woh, xh);

    // qkv GEMM (all-bf16 operands, DMA staging) with fused Q/K/V emission
    gemm_qkv<<<dim3((3 * DM) / 128, M / 128), 256, 0, stream>>>(
        xh, Wqh, Qhp, Khp, Vthp, M, 3 * DM, DM);

    flash_mfma<<<dim3((SEQ / 64) * NH * NB), 256, FLASH_LDS, stream>>>(
        Qhp, Khp, Vthp, attn);

    gemm_out<<<dim3(DM / 128, M / 128), 256, 0, stream>>>(
        attn, Woh, out, M, DM, DM);
}

// Round 25
// 117.187 us; speedup vs baseline: 1.1666x; 1.1666x over previous
//
#include <hip/hip_runtime.h>
#include <hip/hip_bf16.h>

#define SEQ 4096
#define NB 2
#define DM 512
#define NH 8
#define DK 64

typedef __bf16 bf16;
typedef __bf16 bf16x4 __attribute__((ext_vector_type(4)));
typedef __bf16 bf16x8 __attribute__((ext_vector_type(8)));
typedef float  f32x4 __attribute__((ext_vector_type(4)));

__device__ __forceinline__ f32x4 mfma16(bf16x8 a, bf16x8 b, f32x4 c) {
    return __builtin_amdgcn_mfma_f32_16x16x32_bf16(a, b, c, 0, 0, 0);
}

__device__ __forceinline__ float fexp2(float x) {
    return __builtin_amdgcn_exp2f(x);   // raw v_exp_f32 (2^x)
}

// Async global->LDS, 16B per lane. LDS dest is wave-uniform base + lane*16.
__device__ __forceinline__ void gload_lds16(const bf16* g, bf16* l) {
    __builtin_amdgcn_global_load_lds(
        (const __attribute__((address_space(1))) void*)g,
        (__attribute__((address_space(3))) void*)l, 16, 0, 0);
}

// LDS rows are 64 bf16 (128 B). XOR-swizzle 16B slot by row (G4 fix).
__device__ __forceinline__ int swzE(int row, int e) {
    return row * 64 + (e ^ ((row & 7) << 3));
}

// Load 8 contiguous fp32 -> bf16x8 (hi only).
__device__ __forceinline__ bf16x8 cvt8(const float* __restrict__ p) {
    const float4 v0 = *(const float4*)p;
    const float4 v1 = *(const float4*)(p + 4);
    return (bf16x8){(bf16)v0.x, (bf16)v0.y, (bf16)v0.z, (bf16)v0.w,
                    (bf16)v1.x, (bf16)v1.y, (bf16)v1.z, (bf16)v1.w};
}

// ---------------------------------------------------------------------------
// Prep, one launch: weight transposes to bf16 AND x -> bf16 copy.
// by 0..23: Wqkv -> Wqh[1536][512]; by 24..31: Wout -> Woh[512][512];
// by 32..39: x (8192x512 fp32) -> xh bf16.
// ---------------------------------------------------------------------------
__global__ __launch_bounds__(256)
void prep_all(const float* __restrict__ Wqkv, const float* __restrict__ Wout,
              const float* __restrict__ x,
              bf16* __restrict__ Wqh, bf16* __restrict__ Woh,
              bf16* __restrict__ xh) {
    __shared__ float T[64][65];
    const int t = threadIdx.x;
    const int bx = blockIdx.x, by = blockIdx.y;

    if (by >= 32) {   // x conversion
        const int r0 = ((by - 32) * 8 + bx) * 128;
        #pragma unroll
        for (int i = 0; i < 32; ++i) {
            const int idx = i * 256 + t;
            const int rr = idx >> 6;
            const int cc = (idx & 63) * 8;
            const size_t o = (size_t)(r0 + rr) * DM + cc;
            *(bf16x8*)&xh[o] = cvt8(&x[o]);
        }
        return;
    }

    const float* W; bf16* D; int N, n0;
    if (by < 24) { W = Wqkv; D = Wqh; N = 3 * DM; n0 = by * 64; }
    else         { W = Wout; D = Woh; N = DM;     n0 = (by - 24) * 64; }
    const int k0 = bx * 64;
    #pragma unroll
    for (int i = 0; i < 4; ++i) {
        int r = i * 16 + (t >> 4);
        int c = (t & 15) * 4;
        float4 v = *(const float4*)&W[(size_t)(k0 + r) * N + n0 + c];
        T[r][c + 0] = v.x; T[r][c + 1] = v.y; T[r][c + 2] = v.z; T[r][c + 3] = v.w;
    }
    __syncthreads();
    #pragma unroll
    for (int i = 0; i < 4; ++i) {
        int n = i * 16 + (t >> 4);
        int c = (t & 15) * 4;
        bf16x4 hv = (bf16x4){(bf16)T[c + 0][n], (bf16)T[c + 1][n],
                             (bf16)T[c + 2][n], (bf16)T[c + 3][n]};
        *(bf16x4*)&D[(size_t)(n0 + n) * DM + k0 + c] = hv;
    }
}

// ---------------------------------------------------------------------------
// QKV GEMM: all-bf16 operands, pure global_load_lds staging; fused bf16
// Q/K/V emission via LDS bounce (Q scaled by log2e/8; V transposed + R20
// slot permutation).
// ---------------------------------------------------------------------------
__global__ __launch_bounds__(256, 2)
void gemm_qkv(const bf16* __restrict__ A, const bf16* __restrict__ Bth,
              bf16* __restrict__ Qout, bf16* __restrict__ Kout,
              bf16* __restrict__ Vout, int M, int N, int K) {
    __shared__ __align__(16) char smem_raw[36864];   // 36 KB
    bf16* Ah = (bf16*)smem_raw;
    bf16* Bh = Ah + 128 * 64;

    const int t = threadIdx.x;
    const int lane = t & 63, w = t >> 6;
    const int l15 = lane & 15, g = lane >> 4;
    const int wm = (w >> 1) * 64, wn = (w & 1) * 64;
    const int rowA = blockIdx.y * 128;
    const int colB = blockIdx.x * 128;

    const int sr2 = t >> 3;
    const int sc8 = (t & 7) * 8;
    const int scs = sc8 ^ ((sr2 & 7) << 3);
    const int dstE = t * 8;

    f32x4 acc[4][4] = {};

    for (int k0 = 0; k0 < K; k0 += 64) {
        __syncthreads();
        #pragma unroll
        for (int c = 0; c < 4; ++c) {
            gload_lds16(&A[(size_t)(rowA + c * 32 + sr2) * K + k0 + scs],
                        Ah + c * 2048 + dstE);
            gload_lds16(&Bth[(size_t)(colB + c * 32 + sr2) * K + k0 + scs],
                        Bh + c * 2048 + dstE);
        }
        __syncthreads();
        #pragma unroll
        for (int kst = 0; kst < 2; ++kst) {
            bf16x8 ah[4];
            #pragma unroll
            for (int mi = 0; mi < 4; ++mi) {
                int off = swzE(wm + mi * 16 + l15, kst * 32 + g * 8);
                ah[mi] = *(const bf16x8*)&Ah[off];
            }
            #pragma unroll
            for (int ni = 0; ni < 4; ++ni) {
                int off = swzE(wn + ni * 16 + l15, kst * 32 + g * 8);
                bf16x8 bh = *(const bf16x8*)&Bh[off];
                #pragma unroll
                for (int mi = 0; mi < 4; ++mi)
                    acc[mi][ni] = mfma16(ah[mi], bh, acc[mi][ni]);
            }
        }
    }

    // ---- fused Q/K/V bf16 epilogue via LDS bounce ----
    const int sec = colB >> 9;           // 0=Q, 1=K, 2=V
    const float scl = (sec == 0) ? 0.125f * 1.44269504088896f : 1.0f;
    bf16* TB = (bf16*)smem_raw;          // [128][136] bf16
    __syncthreads();
    #pragma unroll
    for (int mi = 0; mi < 4; ++mi)
        #pragma unroll
        for (int ni = 0; ni < 4; ++ni)
            #pragma unroll
            for (int r = 0; r < 4; ++r) {
                const int rr = wm + mi * 16 + g * 4 + r;
                const int cr = wn + ni * 16 + l15;
                const float v = acc[mi][ni][r] * scl;
                if (sec < 2) {
                    TB[rr * 136 + cr] = (bf16)v;
                } else {
                    const int kk = rr & 63;
                    const int nn = kk >> 4;
                    const int sl = ((nn & 1) << 5) | (((kk >> 2) & 3) << 3)
                                 | ((nn >> 1) << 2) | (kk & 3);
                    TB[cr * 136 + (rr >> 6) * 64 + sl] = (bf16)v;
                }
            }
    __syncthreads();
    const int b_ = rowA >> 12;
    const int sbase = rowA & 4095;
    #pragma unroll
    for (int pass = 0; pass < 8; ++pass) {
        const int rowi = pass * 16 + (t >> 4);
        const int e8 = (t & 15) * 8;
        bf16x8 v = *(const bf16x8*)&TB[rowi * 136 + e8];
        if (sec < 2) {
            const int ckv = (colB & 511) + e8;
            const int h_ = ckv >> 6, d8 = ckv & 63;
            bf16* dst = (sec == 0) ? Qout : Kout;
            *(bf16x8*)&dst[(((size_t)b_ * NH + h_) * SEQ + sbase + rowi) * DK + d8] = v;
        } else {
            const int cv = (colB - 1024) + rowi;
            const int h_ = cv >> 6, d_ = cv & 63;
            *(bf16x8*)&Vout[(((size_t)b_ * NH + h_) * DK + d_) * SEQ + sbase + e8] = v;
        }
    }
}

// ---------------------------------------------------------------------------
// Out GEMM: both operands bf16 -> pure gload_lds staging. fp32 C.
// ---------------------------------------------------------------------------
__global__ __launch_bounds__(256, 2)
void gemm_out(const bf16* __restrict__ A, const bf16* __restrict__ Bth,
              float* __restrict__ C, int M, int N, int K) {
    __shared__ __align__(16) bf16 Ah[128 * 64], Bh[128 * 64];

    const int t = threadIdx.x;
    const int lane = t & 63, w = t >> 6;
    const int l15 = lane & 15, g = lane >> 4;
    const int wm = (w >> 1) * 64, wn = (w & 1) * 64;
    const int rowA = blockIdx.y * 128;
    const int colB = blockIdx.x * 128;

    const int sr2 = t >> 3;
    const int sc8 = (t & 7) * 8;
    const int scs = sc8 ^ ((sr2 & 7) << 3);
    const int dstE = t * 8;

    f32x4 acc[4][4] = {};

    for (int k0 = 0; k0 < K; k0 += 64) {
        __syncthreads();
        #pragma unroll
        for (int c = 0; c < 4; ++c) {
            gload_lds16(&A[(size_t)(rowA + c * 32 + sr2) * K + k0 + scs],
                        Ah + c * 2048 + dstE);
            gload_lds16(&Bth[(size_t)(colB + c * 32 + sr2) * K + k0 + scs],
                        Bh + c * 2048 + dstE);
        }
        __syncthreads();
        #pragma unroll
        for (int kst = 0; kst < 2; ++kst) {
            bf16x8 ah[4];
            #pragma unroll
            for (int mi = 0; mi < 4; ++mi) {
                int off = swzE(wm + mi * 16 + l15, kst * 32 + g * 8);
                ah[mi] = *(const bf16x8*)&Ah[off];
            }
            #pragma unroll
            for (int ni = 0; ni < 4; ++ni) {
                int off = swzE(wn + ni * 16 + l15, kst * 32 + g * 8);
                bf16x8 bh = *(const bf16x8*)&Bh[off];
                #pragma unroll
                for (int mi = 0; mi < 4; ++mi)
                    acc[mi][ni] = mfma16(ah[mi], bh, acc[mi][ni]);
            }
        }
    }
    #pragma unroll
    for (int mi = 0; mi < 4; ++mi)
        #pragma unroll
        for (int ni = 0; ni < 4; ++ni)
            #pragma unroll
            for (int r = 0; r < 4; ++r) {
                int row = rowA + wm + mi * 16 + g * 4 + r;
                int col = colB + wn + ni * 16 + l15;
                C[(size_t)row * N + col] = acc[mi][ni][r];
            }
}

// ---------------------------------------------------------------------------
// MFMA flash attention — R23-exact revert (R24's 256-thread blocks halved
// the compute each staged K/V tile amortizes: staging VALU+L2 doubled per
// unit MFMA, 74->94 us). 512 threads, 128 q-rows/block, 8 waves x 16 rows;
// swapped QK^T -> P lane-local in-register packing; no-max exp2 softmax;
// l via ones-MFMA; single-stream 2-phase dbuf + gload_lds; bf16 epilogue.
// LDS 32 KB -> 2 blocks/CU (grid 512 = 2/CU exactly).
// ---------------------------------------------------------------------------
__global__ __launch_bounds__(512)
void flash_mfma(const bf16* __restrict__ Qh,
                const bf16* __restrict__ Kh, const bf16* __restrict__ Vth,
                bf16* __restrict__ att) {
    extern __shared__ bf16 smem[];
    bf16* KhS = smem;              // [2][64*64] dbuf, 16 KB
    bf16* VhS = smem + 8192;       // [2][64*64] dbuf, 16 KB  -> total 32 KB

    // XCD-bijective swizzle: nwg = 512 (divisible by 8).
    const int nwg = (int)gridDim.x;
    const int cpx = nwg >> 3;
    const int bid = (int)blockIdx.x;
    const int wg = (bid & 7) * cpx + (bid >> 3);
    const int qt = wg & 31;        // 32 q-tiles of 128 rows
    const int bh = wg >> 5;

    const int t = threadIdx.x, lane = t & 63, w = t >> 6;   // 8 waves
    const int l15 = lane & 15, g = lane >> 4;
    const int q0 = qt * 128;
    const int wq = w * 16;   // each wave owns 16 q-rows

    // Q fragments: pre-scaled bf16, direct load (B-operand for swapped QK^T)
    bf16x8 qh[2];
    {
        const size_t qbase = ((size_t)bh * SEQ + q0 + wq + l15) * DK + g * 8;
        qh[0] = *(const bf16x8*)&Qh[qbase];
        qh[1] = *(const bf16x8*)&Qh[qbase + 32];
    }

    const bf16 one = (bf16)1.0f;
    const bf16x8 ones = (bf16x8){one, one, one, one, one, one, one, one};

    f32x4 o[4] = {};
    f32x4 lacc = {0.f, 0.f, 0.f, 0.f};

    // Staging: LDS dest = wave base + lane*16B (global_load_lds pattern);
    // global source column pre-swizzled (G21 both-sides rule).
    const int sr = t >> 3;
    const int sc8 = (t & 7) * 8;
    const int scs = sc8 ^ ((sr & 7) << 3);
    const size_t kgo = ((size_t)bh * SEQ + sr) * DK + scs;
    const size_t vgo = ((size_t)bh * DK + sr) * SEQ + scs;
    const int dst = t * 8;   // element offset within a [64*64] buffer

    auto stage = [&](int kt, int c) {
        const int cb = c * 4096 + dst;
        gload_lds16(Kh + kgo + (size_t)kt * 64 * DK, KhS + cb);
        gload_lds16(Vth + vgo + (size_t)kt * 64,     VhS + cb);
    };

    const int NT = SEQ / 64;
    stage(0, 0);
    __syncthreads();   // drain tile-0 DMA

    for (int kt = 0; kt < NT; ++kt) {
        const int c = kt & 1;
        if (kt + 1 < NT) stage(kt + 1, c ^ 1);   // async loads overlap compute
        const int cb = c * 4096;

        // ---- scores, SWAPPED: s[ni] = K_tile(ni) @ Q -> [k-row][q-col] ----
        f32x4 s[4] = {};
        __builtin_amdgcn_s_setprio(1);
        #pragma unroll
        for (int kst = 0; kst < 2; ++kst) {
            #pragma unroll
            for (int ni = 0; ni < 4; ++ni) {
                int off = cb + swzE(ni * 16 + l15, kst * 32 + g * 8);
                bf16x8 kh_ = *(const bf16x8*)&KhS[off];
                s[ni] = mfma16(kh_, qh[kst], s[ni]);
            }
        }
        __builtin_amdgcn_s_setprio(0);

        // ---- P = exp2(s), packed IN REGISTERS to the PV A-fragment ----
        bf16x8 pa[2];
        #pragma unroll
        for (int ni = 0; ni < 4; ++ni)
            #pragma unroll
            for (int r = 0; r < 4; ++r)
                pa[ni & 1][(ni >> 1) * 4 + r] = (bf16)fexp2(s[ni][r]);

        // ---- O += P @ V; l += P @ 1 (row sums on the matrix pipe) ----
        __builtin_amdgcn_s_setprio(1);
        #pragma unroll
        for (int kst = 0; kst < 2; ++kst) {
            #pragma unroll
            for (int ni = 0; ni < 4; ++ni) {
                int off = cb + swzE(ni * 16 + l15, kst * 32 + g * 8);
                bf16x8 vh_ = *(const bf16x8*)&VhS[off];
                o[ni] = mfma16(pa[kst], vh_, o[ni]);
            }
            lacc = mfma16(pa[kst], ones, lacc);
        }
        __builtin_amdgcn_s_setprio(0);

        __syncthreads();   // drains next-tile DMA; fences buffer reuse
    }

    // ---- epilogue: normalize, store bf16 ----
    const int b = bh >> 3, h = bh & 7;
    #pragma unroll
    for (int r = 0; r < 4; ++r) {
        const float inv = 1.0f / lacc[r];
        const int row = q0 + wq + g * 4 + r;
        #pragma unroll
        for (int ni = 0; ni < 4; ++ni)
            att[(size_t)(b * SEQ + row) * DM + h * DK + ni * 16 + l15] =
                (bf16)(o[ni][r] * inv);
    }
}

// ---------------------------------------------------------------------------
extern "C" void kernel_launch(void* const* d_in, const int* in_sizes, int n_in,
                              void* d_out, int out_size, void* d_ws, size_t ws_size,
                              hipStream_t stream) {
    const float* x    = (const float*)d_in[0];
    const float* Wqkv = (const float*)d_in[1];
    const float* Wout = (const float*)d_in[2];
    float* out = (float*)d_out;

    char* ws = (char*)d_ws;
    bf16* Qhp  = (bf16*)(ws);                            // 8 MB
    bf16* xh   = (bf16*)(ws + (size_t)16 * 1048576);     // 8 MB
    bf16* attn = (bf16*)(ws + (size_t)48 * 1048576);     // 8 MB
    bf16* Khp  = (bf16*)(ws + (size_t)64 * 1048576);     // 8 MB
    bf16* Vthp = (bf16*)(ws + (size_t)80 * 1048576);     // 8 MB
    bf16* Wqh  = (bf16*)(ws + (size_t)96 * 1048576);     // 1.5 MB
    bf16* Woh  = (bf16*)(ws + (size_t)100 * 1048576);    // 0.5 MB

    const int M = NB * SEQ;   // 8192
    const int FLASH_LDS = 32768;   // 32 KB: Kh[2] + Vh[2]

    hipFuncSetAttribute((const void*)flash_mfma,
                        hipFuncAttributeMaxDynamicSharedMemorySize, FLASH_LDS);

    // weight transposes + x bf16 conversion, one launch
    prep_all<<<dim3(8, 40), 256, 0, stream>>>(Wqkv, Wout, x, Wqh, Woh, xh);

    // qkv GEMM (all-bf16 operands, DMA staging) with fused Q/K/V emission
    gemm_qkv<<<dim3((3 * DM) / 128, M / 128), 256, 0, stream>>>(
        xh, Wqh, Qhp, Khp, Vthp, M, 3 * DM, DM);

    flash_mfma<<<dim3((SEQ / 128) * NH * NB), 512, FLASH_LDS, stream>>>(
        Qhp, Khp, Vthp, attn);

    gemm_out<<<dim3(DM / 128, M / 128), 256, 0, stream>>>(
        attn, Woh, out, M, DM, DM);
}